// Round 8
// baseline (863.147 us; speedup 1.0000x reference)
//
#include <hip/hip_runtime.h>
#include <cstddef>

typedef unsigned short u16;
typedef __attribute__((ext_vector_type(8))) short bf16x8;   // 8 bf16 = 4 VGPRs
typedef __attribute__((ext_vector_type(4))) float f32x4;    // MFMA 16x16 accumulator

__device__ __forceinline__ u16 f2b(float f) {
    union { float f; unsigned u; } x; x.f = f;
    unsigned r = x.u + 0x7FFFu + ((x.u >> 16) & 1u);   // round-to-nearest-even
    return (u16)(r >> 16);
}
__device__ __forceinline__ float b2f(u16 v) {
    union { unsigned u; float f; } x; x.u = ((unsigned)v) << 16;
    return x.f;
}

__device__ __forceinline__ void gload_lds16(const u16* g, u16* l) {
    __builtin_amdgcn_global_load_lds(
        (const __attribute__((address_space(1))) void*)g,
        (__attribute__((address_space(3))) void*)l, 16, 0, 0);
}

// ---------------------------------------------------------------------------
// bf16 MFMA GEMM: C[M,N] = A[M,K] @ Bt[N,K]^T (+bias)(+relu)
// 128x128 tile, BK=64 (32 KB LDS, halves barriers vs BK=32), 4 waves.
// Output fp32 (Cf) or bf16 (Cb). Requires K%64==0, N%128==0; M ragged.
// ---------------------------------------------------------------------------
__global__ __launch_bounds__(256) void gemm_mfma_kernel(
    const u16* __restrict__ A, const u16* __restrict__ Bt,
    const float* __restrict__ bias,
    float* __restrict__ Cf, u16* __restrict__ Cb,
    int M, int K, int N, int relu)
{
    __shared__ __align__(16) u16 As[128 * 64];   // [m][64k], 128B rows
    __shared__ __align__(16) u16 Bs[128 * 64];   // [n][64k]

    const int tid  = threadIdx.x;
    const int wave = tid >> 6;
    const int lane = tid & 63;
    const int m0 = blockIdx.y * 128;
    const int n0 = blockIdx.x * 128;

    const int wm = (wave & 1) * 64;
    const int wn = (wave >> 1) * 64;

    const int srow  = lane >> 3;        // 0..7
    const int skoff = (lane & 7) * 8;   // 0..56

    f32x4 acc[4][4];
#pragma unroll
    for (int i = 0; i < 4; ++i)
#pragma unroll
        for (int j = 0; j < 4; ++j)
            acc[i][j] = (f32x4){0.f, 0.f, 0.f, 0.f};

    const int fm = lane & 15;
    const int fq = (lane >> 4) * 8;

    for (int k0 = 0; k0 < K; k0 += 64) {
        __syncthreads();
        {
            const int r0 = wave * 32;
#pragma unroll
            for (int t = 0; t < 4; ++t) {
                int gr = m0 + r0 + t * 8 + srow; if (gr >= M) gr = M - 1;
                gload_lds16(A + (size_t)gr * K + k0 + skoff, &As[(r0 + t * 8) * 64]);
                gload_lds16(Bt + (size_t)(n0 + r0 + t * 8 + srow) * K + k0 + skoff,
                            &Bs[(r0 + t * 8) * 64]);
            }
        }
        __syncthreads();

#pragma unroll
        for (int kk = 0; kk < 64; kk += 32) {
            bf16x8 af[4], bfr[4];
#pragma unroll
            for (int t = 0; t < 4; ++t) {
                af[t]  = *(const bf16x8*)(&As[(wm + t * 16 + fm) * 64 + fq + kk]);
                bfr[t] = *(const bf16x8*)(&Bs[(wn + t * 16 + fm) * 64 + fq + kk]);
            }
#pragma unroll
            for (int i = 0; i < 4; ++i)
#pragma unroll
                for (int j = 0; j < 4; ++j)
                    acc[i][j] = __builtin_amdgcn_mfma_f32_16x16x32_bf16(
                        af[i], bfr[j], acc[i][j], 0, 0, 0);
        }
    }

    const int col = lane & 15;
    const int rq  = (lane >> 4) * 4;
#pragma unroll
    for (int j = 0; j < 4; ++j) {
        const int gn = n0 + wn + j * 16 + col;
        const float bb = bias ? bias[gn] : 0.f;
#pragma unroll
        for (int i = 0; i < 4; ++i) {
            const int gmb = m0 + wm + i * 16 + rq;
#pragma unroll
            for (int r = 0; r < 4; ++r) {
                const int gm = gmb + r;
                if (gm < M) {
                    float v = acc[i][j][r] + bb;
                    if (relu) v = fmaxf(v, 0.f);
                    if (Cb) Cb[(size_t)gm * N + gn] = f2b(v);
                    else    Cf[(size_t)gm * N + gn] = v;
                }
            }
        }
    }
}

// ---------------------------------------------------------------------------
// Small-tile bf16 MFMA GEMM for skinny-M (decoder): 64x64 tile, BK=64.
// ---------------------------------------------------------------------------
__global__ __launch_bounds__(256) void gemm64_kernel(
    const u16* __restrict__ A, const u16* __restrict__ Bt,
    const float* __restrict__ bias,
    float* __restrict__ Cf, u16* __restrict__ Cb,
    int M, int K, int N, int relu)
{
    __shared__ __align__(16) u16 As[64 * 64];
    __shared__ __align__(16) u16 Bs[64 * 64];

    const int tid  = threadIdx.x;
    const int wave = tid >> 6;
    const int lane = tid & 63;
    const int m0 = blockIdx.y * 64;
    const int n0 = blockIdx.x * 64;
    const int wm = (wave & 1) * 32;
    const int wn = (wave >> 1) * 32;

    const int srow  = lane >> 3;        // 0..7
    const int skoff = (lane & 7) * 8;

    f32x4 acc[2][2];
#pragma unroll
    for (int i = 0; i < 2; ++i)
#pragma unroll
        for (int j = 0; j < 2; ++j) acc[i][j] = (f32x4){0.f, 0.f, 0.f, 0.f};

    const int fm = lane & 15;
    const int fq = (lane >> 4) * 8;

    for (int k0 = 0; k0 < K; k0 += 64) {
        __syncthreads();
        {
#pragma unroll
            for (int t = 0; t < 2; ++t) {
                int gr = m0 + t * 32 + wave * 8 + srow; if (gr >= M) gr = M - 1;
                gload_lds16(A + (size_t)gr * K + k0 + skoff, &As[(t * 32 + wave * 8) * 64]);
                gload_lds16(Bt + (size_t)(n0 + t * 32 + wave * 8 + srow) * K + k0 + skoff,
                            &Bs[(t * 32 + wave * 8) * 64]);
            }
        }
        __syncthreads();

#pragma unroll
        for (int kk = 0; kk < 64; kk += 32) {
            bf16x8 af[2], bfr[2];
#pragma unroll
            for (int t = 0; t < 2; ++t) {
                af[t]  = *(const bf16x8*)(&As[(wm + t * 16 + fm) * 64 + fq + kk]);
                bfr[t] = *(const bf16x8*)(&Bs[(wn + t * 16 + fm) * 64 + fq + kk]);
            }
#pragma unroll
            for (int i = 0; i < 2; ++i)
#pragma unroll
                for (int j = 0; j < 2; ++j)
                    acc[i][j] = __builtin_amdgcn_mfma_f32_16x16x32_bf16(
                        af[i], bfr[j], acc[i][j], 0, 0, 0);
        }
    }

    const int col = lane & 15;
    const int rq  = (lane >> 4) * 4;
#pragma unroll
    for (int j = 0; j < 2; ++j) {
        const int gn = n0 + wn + j * 16 + col;
        const float bb = bias ? bias[gn] : 0.f;
#pragma unroll
        for (int i = 0; i < 2; ++i) {
            const int gmb = m0 + wm + i * 16 + rq;
#pragma unroll
            for (int r = 0; r < 4; ++r) {
                const int gm = gmb + r;
                if (gm < M) {
                    float v = acc[i][j][r] + bb;
                    if (relu) v = fmaxf(v, 0.f);
                    if (Cb) Cb[(size_t)gm * N + gn] = f2b(v);
                    else    Cf[(size_t)gm * N + gn] = v;
                }
            }
        }
    }
}

// ---------------------------------------------------------------------------
// bf16 MFMA flash attention, q-tile 128, k-tile 128 (two 64-k sub-tiles per
// barrier round: halves barrier count), NO-RESCALE softmax (O(1) scores).
// LDS: Ks[128][72] + Vs[64][144] (transposed) + Ps[128][144] = 73.7 KB.
// Requires Lk%128==0; Lq ragged.
// ---------------------------------------------------------------------------
__global__ __launch_bounds__(256) void attn_mfma_kernel(
    const u16* __restrict__ Qp, const u16* __restrict__ Kp,
    const u16* __restrict__ Vp, u16* __restrict__ Op,
    int Lq, int Lk, int ldq, int ldkv, int ldo)
{
    const int q0 = blockIdx.x * 128;
    const int h  = blockIdx.y;
    const int b  = blockIdx.z;
    const int tid  = threadIdx.x;
    const int wave = tid >> 6;
    const int lane = tid & 63;
    const int c = lane & 15;
    const int g = lane >> 4;
    const float scale = 0.125f;

    __shared__ __align__(16) u16 Ks[128 * 72];    // [k][d]
    __shared__ __align__(16) u16 Vs[64 * 144];    // transposed: [d][k], k=0..127
    __shared__ __align__(16) u16 Ps[128 * 144];   // [q][k], k=0..127

    bf16x8 aq[2][2];
#pragma unroll
    for (int half = 0; half < 2; ++half) {
        int qrow = q0 + wave * 32 + half * 16 + c;
        if (qrow > Lq - 1) qrow = Lq - 1;
        const u16* src = Qp + ((size_t)(b * Lq + qrow)) * ldq + h * 64 + g * 8;
        aq[half][0] = *(const bf16x8*)(src);
        aq[half][1] = *(const bf16x8*)(src + 32);
    }

    float den[2][4] = {};
    f32x4 o[2][4];
#pragma unroll
    for (int half = 0; half < 2; ++half)
#pragma unroll
        for (int j = 0; j < 4; ++j) o[half][j] = (f32x4){0.f, 0.f, 0.f, 0.f};

    const int srow = tid & 63;
    const int sseg = tid >> 6;

    for (int t = 0; t < (Lk >> 7); ++t) {
        const int k0 = t << 7;
        __syncthreads();
#pragma unroll
        for (int sub = 0; sub < 2; ++sub) {
            const int kr = k0 + sub * 64 + srow;
            const u16* kg = Kp + ((size_t)(b * Lk + kr)) * ldkv + h * 64;
            *(bf16x8*)(&Ks[(sub * 64 + srow) * 72 + sseg * 8])      = *(const bf16x8*)(kg + sseg * 8);
            *(bf16x8*)(&Ks[(sub * 64 + srow) * 72 + 32 + sseg * 8]) = *(const bf16x8*)(kg + 32 + sseg * 8);
            const u16* vg = Vp + ((size_t)(b * Lk + kr)) * ldkv + h * 64;
            bf16x8 v0 = *(const bf16x8*)(vg + sseg * 8);
            bf16x8 v1 = *(const bf16x8*)(vg + 32 + sseg * 8);
#pragma unroll
            for (int i = 0; i < 8; ++i) {
                Vs[(sseg * 8 + i) * 144 + sub * 64 + srow]      = (u16)v0[i];
                Vs[(32 + sseg * 8 + i) * 144 + sub * 64 + srow] = (u16)v1[i];
            }
        }
        __syncthreads();

        // ---- S = Q K^T over 128 keys; exp; Ps ----
#pragma unroll
        for (int half = 0; half < 2; ++half) {
            f32x4 s[8];
#pragma unroll
            for (int jn = 0; jn < 8; ++jn) s[jn] = (f32x4){0.f, 0.f, 0.f, 0.f};
#pragma unroll
            for (int jn = 0; jn < 8; ++jn) {
                bf16x8 b0 = *(const bf16x8*)(&Ks[(jn * 16 + c) * 72 + g * 8]);
                bf16x8 b1 = *(const bf16x8*)(&Ks[(jn * 16 + c) * 72 + 32 + g * 8]);
                s[jn] = __builtin_amdgcn_mfma_f32_16x16x32_bf16(aq[half][0], b0, s[jn], 0, 0, 0);
                s[jn] = __builtin_amdgcn_mfma_f32_16x16x32_bf16(aq[half][1], b1, s[jn], 0, 0, 0);
            }
#pragma unroll
            for (int jn = 0; jn < 8; ++jn)
#pragma unroll
                for (int r = 0; r < 4; ++r) {
                    const float p = __expf(s[jn][r] * scale);
                    den[half][r] += p;
                    Ps[(wave * 32 + half * 16 + g * 4 + r) * 144 + jn * 16 + c] = f2b(p);
                }
        }

        __asm__ volatile("s_waitcnt lgkmcnt(0)" ::: "memory");   // in-wave Ps order

        // ---- O += P V over the two 64-k sub-tiles ----
#pragma unroll
        for (int half = 0; half < 2; ++half) {
            const int qr = (wave * 32 + half * 16 + c) * 144;
#pragma unroll
            for (int sub = 0; sub < 2; ++sub) {
                bf16x8 ap0 = *(const bf16x8*)(&Ps[qr + sub * 64 + g * 8]);
                bf16x8 ap1 = *(const bf16x8*)(&Ps[qr + sub * 64 + 32 + g * 8]);
#pragma unroll
                for (int jd = 0; jd < 4; ++jd) {
                    bf16x8 b0 = *(const bf16x8*)(&Vs[(jd * 16 + c) * 144 + sub * 64 + g * 8]);
                    bf16x8 b1 = *(const bf16x8*)(&Vs[(jd * 16 + c) * 144 + sub * 64 + 32 + g * 8]);
                    o[half][jd] = __builtin_amdgcn_mfma_f32_16x16x32_bf16(ap0, b0, o[half][jd], 0, 0, 0);
                    o[half][jd] = __builtin_amdgcn_mfma_f32_16x16x32_bf16(ap1, b1, o[half][jd], 0, 0, 0);
                }
            }
        }
    }

#pragma unroll
    for (int half = 0; half < 2; ++half)
#pragma unroll
        for (int r = 0; r < 4; ++r) {
#pragma unroll
            for (int msk = 1; msk < 16; msk <<= 1)
                den[half][r] += __shfl_xor(den[half][r], msk, 64);
        }

#pragma unroll
    for (int half = 0; half < 2; ++half)
#pragma unroll
        for (int r = 0; r < 4; ++r) {
            const int q = q0 + wave * 32 + half * 16 + g * 4 + r;
            if (q < Lq) {
                const float inv = 1.0f / den[half][r];
#pragma unroll
                for (int jd = 0; jd < 4; ++jd)
                    Op[((size_t)(b * Lq + q)) * ldo + h * 64 + jd * 16 + c] =
                        f2b(o[half][jd][r] * inv);
            }
        }
}

// ---------------------------------------------------------------------------
// CAUSAL (post-softmax -1e10 fill) MFMA attention:
//   O[q] = (sum_{k<=q} e_k V_k)/den + (-1e10)*suffV[q], den over all k<Lk.
// q-tile 128, k-tile 64 (Lk=100: 2 ragged tiles).
// ---------------------------------------------------------------------------
__global__ __launch_bounds__(256) void attn_causal_kernel(
    const u16* __restrict__ Qp, const u16* __restrict__ Kp,
    const u16* __restrict__ Vp, const float* __restrict__ SuffV,
    u16* __restrict__ Op,
    int Lq, int Lk, int ldq, int ldkv, int ldo)
{
    const int q0 = blockIdx.x * 128;
    const int h  = blockIdx.y;
    const int b  = blockIdx.z;
    const int tid  = threadIdx.x;
    const int wave = tid >> 6;
    const int lane = tid & 63;
    const int c = lane & 15;
    const int g = lane >> 4;
    const float scale = 0.125f;

    __shared__ __align__(16) u16 Ks[64 * 72];
    __shared__ __align__(16) u16 Vs[64 * 72];
    __shared__ __align__(16) u16 Ps[128 * 72];

    bf16x8 aq[2][2];
#pragma unroll
    for (int half = 0; half < 2; ++half) {
        int qrow = q0 + wave * 32 + half * 16 + c;
        if (qrow > Lq - 1) qrow = Lq - 1;
        const u16* src = Qp + ((size_t)(b * Lq + qrow)) * ldq + h * 64 + g * 8;
        aq[half][0] = *(const bf16x8*)(src);
        aq[half][1] = *(const bf16x8*)(src + 32);
    }

    float den[2][4] = {};
    f32x4 o[2][4];
#pragma unroll
    for (int half = 0; half < 2; ++half)
#pragma unroll
        for (int j = 0; j < 4; ++j) o[half][j] = (f32x4){0.f, 0.f, 0.f, 0.f};

    const int srow = tid & 63;
    const int sseg = tid >> 6;
    const int ntiles = (Lk + 63) >> 6;

    for (int t = 0; t < ntiles; ++t) {
        const int k0 = t << 6;
        __syncthreads();
        {
            int kr = k0 + srow; if (kr > Lk - 1) kr = Lk - 1;
            const u16* kg = Kp + ((size_t)(b * Lk + kr)) * ldkv + h * 64;
            *(bf16x8*)(&Ks[srow * 72 + sseg * 8])      = *(const bf16x8*)(kg + sseg * 8);
            *(bf16x8*)(&Ks[srow * 72 + 32 + sseg * 8]) = *(const bf16x8*)(kg + 32 + sseg * 8);
            const u16* vg = Vp + ((size_t)(b * Lk + kr)) * ldkv + h * 64;
            bf16x8 v0 = *(const bf16x8*)(vg + sseg * 8);
            bf16x8 v1 = *(const bf16x8*)(vg + 32 + sseg * 8);
#pragma unroll
            for (int i = 0; i < 8; ++i) {
                Vs[(sseg * 8 + i) * 72 + srow]      = (u16)v0[i];
                Vs[(32 + sseg * 8 + i) * 72 + srow] = (u16)v1[i];
            }
        }
        __syncthreads();

#pragma unroll
        for (int half = 0; half < 2; ++half) {
            f32x4 s[4];
#pragma unroll
            for (int jn = 0; jn < 4; ++jn) s[jn] = (f32x4){0.f, 0.f, 0.f, 0.f};
#pragma unroll
            for (int jn = 0; jn < 4; ++jn) {
                bf16x8 b0 = *(const bf16x8*)(&Ks[(jn * 16 + c) * 72 + g * 8]);
                bf16x8 b1 = *(const bf16x8*)(&Ks[(jn * 16 + c) * 72 + 32 + g * 8]);
                s[jn] = __builtin_amdgcn_mfma_f32_16x16x32_bf16(aq[half][0], b0, s[jn], 0, 0, 0);
                s[jn] = __builtin_amdgcn_mfma_f32_16x16x32_bf16(aq[half][1], b1, s[jn], 0, 0, 0);
            }
#pragma unroll
            for (int jn = 0; jn < 4; ++jn)
#pragma unroll
                for (int r = 0; r < 4; ++r) {
                    const int kcol = k0 + jn * 16 + c;
                    const int qrow = q0 + wave * 32 + half * 16 + g * 4 + r;
                    const float e = __expf(s[jn][r] * scale);
                    const float ev = (kcol < Lk) ? e : 0.f;
                    den[half][r] += ev;
                    const float pv = (kcol <= qrow) ? ev : 0.f;
                    Ps[(wave * 32 + half * 16 + g * 4 + r) * 72 + jn * 16 + c] = f2b(pv);
                }
        }

        __asm__ volatile("s_waitcnt lgkmcnt(0)" ::: "memory");

#pragma unroll
        for (int half = 0; half < 2; ++half) {
            bf16x8 ap0 = *(const bf16x8*)(&Ps[(wave * 32 + half * 16 + c) * 72 + g * 8]);
            bf16x8 ap1 = *(const bf16x8*)(&Ps[(wave * 32 + half * 16 + c) * 72 + 32 + g * 8]);
#pragma unroll
            for (int jd = 0; jd < 4; ++jd) {
                bf16x8 b0 = *(const bf16x8*)(&Vs[(jd * 16 + c) * 72 + g * 8]);
                bf16x8 b1 = *(const bf16x8*)(&Vs[(jd * 16 + c) * 72 + 32 + g * 8]);
                o[half][jd] = __builtin_amdgcn_mfma_f32_16x16x32_bf16(ap0, b0, o[half][jd], 0, 0, 0);
                o[half][jd] = __builtin_amdgcn_mfma_f32_16x16x32_bf16(ap1, b1, o[half][jd], 0, 0, 0);
            }
        }
    }

#pragma unroll
    for (int half = 0; half < 2; ++half)
#pragma unroll
        for (int r = 0; r < 4; ++r) {
#pragma unroll
            for (int msk = 1; msk < 16; msk <<= 1)
                den[half][r] += __shfl_xor(den[half][r], msk, 64);
        }

#pragma unroll
    for (int half = 0; half < 2; ++half)
#pragma unroll
        for (int r = 0; r < 4; ++r) {
            const int q = q0 + wave * 32 + half * 16 + g * 4 + r;
            if (q < Lq) {
                const float inv = 1.0f / den[half][r];
                const float* sv = SuffV + ((size_t)(b * Lq + q)) * 512 + h * 64;
#pragma unroll
                for (int jd = 0; jd < 4; ++jd)
                    Op[((size_t)(b * Lq + q)) * ldo + h * 64 + jd * 16 + c] =
                        f2b(o[half][jd][r] * inv - 1.0e10f * sv[jd * 16 + c]);
            }
        }
}

// Suffix-sum of V rows (exclusive): SuffV[b][q][h*64+d] = sum_{k>q} V[b][k][...]
__global__ __launch_bounds__(64) void suffv_kernel(
    const u16* __restrict__ Vp, float* __restrict__ SuffV, int Lq, int ldv)
{
    const int b = blockIdx.x;
    const int h = blockIdx.y;
    const int d = threadIdx.x;
    float acc = 0.f;
    for (int q = Lq - 1; q >= 0; --q) {
        SuffV[((size_t)(b * Lq + q)) * 512 + h * 64 + d] = acc;
        acc += b2f(Vp[((size_t)(b * Lq + q)) * ldv + h * 64 + d]);
    }
}

// ---------------------------------------------------------------------------
// Split-K cross attention (q-tile 64): partial unnormalized O + partial den.
// ---------------------------------------------------------------------------
__global__ __launch_bounds__(256) void attn_split_kernel(
    const u16* __restrict__ Qp, const u16* __restrict__ Kp,
    const u16* __restrict__ Vp, float* __restrict__ Opart,
    float* __restrict__ Dpart,
    int Lq, int Lk, int ldq, int ldkv, int nsplit)
{
    const int q0 = blockIdx.x * 64;
    const int h  = blockIdx.y;
    const int b  = blockIdx.z / nsplit;
    const int sp = blockIdx.z % nsplit;
    const int tid  = threadIdx.x;
    const int wave = tid >> 6;
    const int lane = tid & 63;
    const int c = lane & 15;
    const int g = lane >> 4;
    const float scale = 0.125f;
    const int rowsTot = gridDim.z / nsplit * Lq;   // B*Lq

    __shared__ __align__(16) u16 Ks[64 * 72];
    __shared__ __align__(16) u16 Vs[64 * 72];
    __shared__ __align__(16) u16 Ps[64 * 72];

    bf16x8 aq[2];
    {
        int qrow = q0 + wave * 16 + c;
        if (qrow > Lq - 1) qrow = Lq - 1;
        const u16* src = Qp + ((size_t)(b * Lq + qrow)) * ldq + h * 64 + g * 8;
        aq[0] = *(const bf16x8*)(src);
        aq[1] = *(const bf16x8*)(src + 32);
    }

    float den[4] = {0.f, 0.f, 0.f, 0.f};
    f32x4 o[4];
#pragma unroll
    for (int j = 0; j < 4; ++j) o[j] = (f32x4){0.f, 0.f, 0.f, 0.f};

    const int srow = tid & 63;
    const int sseg = tid >> 6;
    const int ntile = (Lk >> 6) / nsplit;

    for (int t = sp * ntile; t < (sp + 1) * ntile; ++t) {
        const int k0 = t << 6;
        __syncthreads();
        {
            const u16* kg = Kp + ((size_t)(b * Lk + k0 + srow)) * ldkv + h * 64;
            *(bf16x8*)(&Ks[srow * 72 + sseg * 8])      = *(const bf16x8*)(kg + sseg * 8);
            *(bf16x8*)(&Ks[srow * 72 + 32 + sseg * 8]) = *(const bf16x8*)(kg + 32 + sseg * 8);
            const u16* vg = Vp + ((size_t)(b * Lk + k0 + srow)) * ldkv + h * 64;
            bf16x8 v0 = *(const bf16x8*)(vg + sseg * 8);
            bf16x8 v1 = *(const bf16x8*)(vg + 32 + sseg * 8);
#pragma unroll
            for (int i = 0; i < 8; ++i) {
                Vs[(sseg * 8 + i) * 72 + srow]      = (u16)v0[i];
                Vs[(32 + sseg * 8 + i) * 72 + srow] = (u16)v1[i];
            }
        }
        __syncthreads();

        f32x4 s[4];
#pragma unroll
        for (int jn = 0; jn < 4; ++jn) s[jn] = (f32x4){0.f, 0.f, 0.f, 0.f};
#pragma unroll
        for (int jn = 0; jn < 4; ++jn) {
            bf16x8 b0 = *(const bf16x8*)(&Ks[(jn * 16 + c) * 72 + g * 8]);
            bf16x8 b1 = *(const bf16x8*)(&Ks[(jn * 16 + c) * 72 + 32 + g * 8]);
            s[jn] = __builtin_amdgcn_mfma_f32_16x16x32_bf16(aq[0], b0, s[jn], 0, 0, 0);
            s[jn] = __builtin_amdgcn_mfma_f32_16x16x32_bf16(aq[1], b1, s[jn], 0, 0, 0);
        }
#pragma unroll
        for (int jn = 0; jn < 4; ++jn)
#pragma unroll
            for (int r = 0; r < 4; ++r) {
                const float p = __expf(s[jn][r] * scale);
                den[r] += p;
                Ps[(wave * 16 + g * 4 + r) * 72 + jn * 16 + c] = f2b(p);
            }

        __asm__ volatile("s_waitcnt lgkmcnt(0)" ::: "memory");

        bf16x8 ap0 = *(const bf16x8*)(&Ps[(wave * 16 + c) * 72 + g * 8]);
        bf16x8 ap1 = *(const bf16x8*)(&Ps[(wave * 16 + c) * 72 + 32 + g * 8]);
#pragma unroll
        for (int jd = 0; jd < 4; ++jd) {
            bf16x8 b0 = *(const bf16x8*)(&Vs[(jd * 16 + c) * 72 + g * 8]);
            bf16x8 b1 = *(const bf16x8*)(&Vs[(jd * 16 + c) * 72 + 32 + g * 8]);
            o[jd] = __builtin_amdgcn_mfma_f32_16x16x32_bf16(ap0, b0, o[jd], 0, 0, 0);
            o[jd] = __builtin_amdgcn_mfma_f32_16x16x32_bf16(ap1, b1, o[jd], 0, 0, 0);
        }
    }

#pragma unroll
    for (int r = 0; r < 4; ++r) {
#pragma unroll
        for (int msk = 1; msk < 16; msk <<= 1)
            den[r] += __shfl_xor(den[r], msk, 64);
    }

#pragma unroll
    for (int r = 0; r < 4; ++r) {
        const int q = q0 + wave * 16 + g * 4 + r;
        if (q < Lq) {
            const size_t prow = (size_t)sp * rowsTot + b * Lq + q;
#pragma unroll
            for (int jd = 0; jd < 4; ++jd)
                Opart[prow * 512 + h * 64 + jd * 16 + c] = o[jd][r];
            if (c == 0) Dpart[prow * 8 + h] = den[r];
        }
    }
}

// ---------------------------------------------------------------------------
// Fused combine + residual + LayerNorm.
// ---------------------------------------------------------------------------
__global__ __launch_bounds__(256) void combine_ln_kernel(
    const float* __restrict__ Opart, const float* __restrict__ Dpart,
    int nsplit, int nrows,
    const float* __restrict__ R,
    const float* __restrict__ g, const float* __restrict__ beta,
    float* __restrict__ O, u16* __restrict__ Ob)
{
    const int row = blockIdx.x * 4 + (threadIdx.x >> 6);
    const int lane = threadIdx.x & 63;
    if (row >= nrows) return;
    const size_t base = (size_t)row * 512 + lane * 8;
    const int h = lane >> 3;

    float sd = 0.f;
    float v[8] = {};
    for (int s = 0; s < nsplit; ++s) {
        sd += Dpart[((size_t)s * nrows + row) * 8 + h];
        const float* op = Opart + ((size_t)s * nrows + row) * 512 + lane * 8;
        float4 a = *(const float4*)(op);
        float4 b = *(const float4*)(op + 4);
        v[0] += a.x; v[1] += a.y; v[2] += a.z; v[3] += a.w;
        v[4] += b.x; v[5] += b.y; v[6] += b.z; v[7] += b.w;
    }
    const float invd = 1.0f / sd;
    {
        float4 a = *(const float4*)(R + base);
        float4 b = *(const float4*)(R + base + 4);
        v[0] = v[0] * invd + a.x; v[1] = v[1] * invd + a.y;
        v[2] = v[2] * invd + a.z; v[3] = v[3] * invd + a.w;
        v[4] = v[4] * invd + b.x; v[5] = v[5] * invd + b.y;
        v[6] = v[6] * invd + b.z; v[7] = v[7] * invd + b.w;
    }

    float sum = 0.f;
#pragma unroll
    for (int i = 0; i < 8; ++i) sum += v[i];
#pragma unroll
    for (int msk = 1; msk < 64; msk <<= 1) sum += __shfl_xor(sum, msk, 64);
    const float mean = sum * (1.0f / 512.0f);

    float var = 0.f;
#pragma unroll
    for (int i = 0; i < 8; ++i) { v[i] -= mean; var += v[i] * v[i]; }
#pragma unroll
    for (int msk = 1; msk < 64; msk <<= 1) var += __shfl_xor(var, msk, 64);
    const float rstd = rsqrtf(var * (1.0f / 512.0f) + 1e-5f);

    float o[8];
#pragma unroll
    for (int i = 0; i < 8; ++i)
        o[i] = v[i] * rstd * g[lane * 8 + i] + beta[lane * 8 + i];

    *(float4*)(O + base)     = make_float4(o[0], o[1], o[2], o[3]);
    *(float4*)(O + base + 4) = make_float4(o[4], o[5], o[6], o[7]);
    if (Ob) {
        bf16x8 ob;
#pragma unroll
        for (int i = 0; i < 8; ++i) ob[i] = (short)f2b(o[i]);
        *(bf16x8*)(Ob + base) = ob;
    }
}

// ---------------------------------------------------------------------------
// Batched weight transpose+convert.
// ---------------------------------------------------------------------------
struct WT9 { const float* src[9]; unsigned dst[9]; unsigned os[9]; };
struct WT4 { const float* src[4]; unsigned dst[4]; int K[4]; int N[4]; };

__device__ __forceinline__ void wtrans_tile(
    const float* Wl, u16* Wtl, int K, int N, int k0, int n0, int tid)
{
    __shared__ float t[32][33];
    const int tr = tid >> 3;
    const int tc = (tid & 7) * 4;
    float4 v = *(const float4*)(Wl + (size_t)(k0 + tr) * N + n0 + tc);
    t[tr][tc] = v.x; t[tr][tc + 1] = v.y; t[tr][tc + 2] = v.z; t[tr][tc + 3] = v.w;
    __syncthreads();
    ushort4 o;
    o.x = f2b(t[tc + 0][tr]); o.y = f2b(t[tc + 1][tr]);
    o.z = f2b(t[tc + 2][tr]); o.w = f2b(t[tc + 3][tr]);
    *(ushort4*)(Wtl + (size_t)(n0 + tr) * K + k0 + tc) = o;
}

__global__ __launch_bounds__(256) void wtrans9_kernel(WT9 d, u16* __restrict__ WB)
{
    const int w = blockIdx.z >> 1;
    const int layer = blockIdx.z & 1;
    const float* Wl = d.src[w] + (size_t)layer * 512 * 512;
    u16* Wtl = WB + d.dst[w] + (size_t)layer * d.os[w];
    wtrans_tile(Wl, Wtl, 512, 512, blockIdx.y * 32, blockIdx.x * 32, threadIdx.x);
}

__global__ __launch_bounds__(256) void wtrans4_kernel(WT4 d, u16* __restrict__ WB)
{
    const int w = blockIdx.z >> 1;
    const int layer = blockIdx.z & 1;
    const int K = d.K[w], N = d.N[w];
    const int k0 = blockIdx.y * 32, n0 = blockIdx.x * 32;
    if (k0 >= K || n0 >= N) return;
    const float* Wl = d.src[w] + (size_t)layer * K * N;
    u16* Wtl = WB + d.dst[w] + (size_t)layer * 1048576;
    wtrans_tile(Wl, Wtl, K, N, k0, n0, threadIdx.x);
}

// ---------------------------------------------------------------------------
// fp32 -> bf16 for the two inputs in one launch.
// ---------------------------------------------------------------------------
__global__ __launch_bounds__(256) void conv2_kernel(
    const float* __restrict__ X0, u16* __restrict__ Y0, int n0,
    const float* __restrict__ X1, u16* __restrict__ Y1, int n1)
{
    int i = (blockIdx.x * 256 + threadIdx.x) * 8;
    const float* X; u16* Y;
    if (i < n0) { X = X0 + i; Y = Y0 + i; }
    else if (i < n0 + n1) { X = X1 + (i - n0); Y = Y1 + (i - n0); }
    else return;
    float4 a = *(const float4*)(X);
    float4 b = *(const float4*)(X + 4);
    ushort4 o0, o1;
    o0.x = f2b(a.x); o0.y = f2b(a.y); o0.z = f2b(a.z); o0.w = f2b(a.w);
    o1.x = f2b(b.x); o1.y = f2b(b.y); o1.z = f2b(b.z); o1.w = f2b(b.w);
    *(ushort4*)(Y) = o0;
    *(ushort4*)(Y + 4) = o1;
}

// ---------------------------------------------------------------------------
// Residual + LayerNorm, one wave per row. X fp32 (Xf) or bf16 (Xb).
// ---------------------------------------------------------------------------
__global__ __launch_bounds__(256) void ln_kernel(
    const float* __restrict__ Xf, const u16* __restrict__ Xb,
    const float* __restrict__ R,
    const float* __restrict__ g, const float* __restrict__ beta,
    float* __restrict__ O, u16* __restrict__ Ob, int nrows)
{
    const int row = blockIdx.x * 4 + (threadIdx.x >> 6);
    const int lane = threadIdx.x & 63;
    if (row >= nrows) return;
    const size_t base = (size_t)row * 512 + lane * 8;

    float v[8];
    if (Xf) {
        float4 a = *(const float4*)(Xf + base);
        float4 b = *(const float4*)(Xf + base + 4);
        v[0] = a.x; v[1] = a.y; v[2] = a.z; v[3] = a.w;
        v[4] = b.x; v[5] = b.y; v[6] = b.z; v[7] = b.w;
    } else {
        bf16x8 xb = *(const bf16x8*)(Xb + base);
#pragma unroll
        for (int i = 0; i < 8; ++i) v[i] = b2f((u16)xb[i]);
    }
    {
        float4 a = *(const float4*)(R + base);
        float4 b = *(const float4*)(R + base + 4);
        v[0] += a.x; v[1] += a.y; v[2] += a.z; v[3] += a.w;
        v[4] += b.x; v[5] += b.y; v[6] += b.z; v[7] += b.w;
    }

    float sum = 0.f;
#pragma unroll
    for (int i = 0; i < 8; ++i) sum += v[i];
#pragma unroll
    for (int msk = 1; msk < 64; msk <<= 1) sum += __shfl_xor(sum, msk, 64);
    const float mean = sum * (1.0f / 512.0f);

    float var = 0.f;
#pragma unroll
    for (int i = 0; i < 8; ++i) { v[i] -= mean; var += v[i] * v[i]; }
#pragma unroll
    for (int msk = 1; msk < 64; msk <<= 1) var += __shfl_xor(var, msk, 64);
    const float rstd = rsqrtf(var * (1.0f / 512.0f) + 1e-5f);

    float o[8];
#pragma unroll
    for (int i = 0; i < 8; ++i)
        o[i] = v[i] * rstd * g[lane * 8 + i] + beta[lane * 8 + i];

    *(float4*)(O + base)     = make_float4(o[0], o[1], o[2], o[3]);
    *(float4*)(O + base + 4) = make_float4(o[4], o[5], o[6], o[7]);
    if (Ob) {
        bf16x8 ob;
#pragma unroll
        for (int i = 0; i < 8; ++i) ob[i] = (short)f2b(o[i]);
        *(bf16x8*)(Ob + base) = ob;
    }
}

// ---------------------------------------------------------------------------
// Orchestration
// ---------------------------------------------------------------------------
extern "C" void kernel_launch(void* const* d_in, const int* in_sizes, int n_in,
                              void* d_out, int out_size, void* d_ws, size_t ws_size,
                              hipStream_t stream)
{
    const int B = 8, T_ENC = 1024, T_DEC = 100, DM = 512, DFF = 2048;
    const int ME = B * T_ENC;  // 8192
    const int MD = B * T_DEC;  // 800
    const int L = 2;
    const int NSPLIT = 4;

    int idx = 0;
    const float* x0    = (const float*)d_in[idx++];
    const float* y0    = (const float*)d_in[idx++];
    const float* eWq   = (const float*)d_in[idx++];
    const float* eWk   = (const float*)d_in[idx++];
    const float* eWv   = (const float*)d_in[idx++];
    const float* eW1   = (const float*)d_in[idx++];
    const float* eB1   = (const float*)d_in[idx++];
    const float* eW2   = (const float*)d_in[idx++];
    const float* eB2   = (const float*)d_in[idx++];
    const float* eLn1g = (const float*)d_in[idx++];
    const float* eLn1b = (const float*)d_in[idx++];
    const float* eLn2g = (const float*)d_in[idx++];
    const float* eLn2b = (const float*)d_in[idx++];
    const float* dWq1  = (const float*)d_in[idx++];
    const float* dWk1  = (const float*)d_in[idx++];
    const float* dWv1  = (const float*)d_in[idx++];
    const float* dWq2  = (const float*)d_in[idx++];
    const float* dWk2  = (const float*)d_in[idx++];
    const float* dWv2  = (const float*)d_in[idx++];
    const float* dW1   = (const float*)d_in[idx++];
    const float* dB1   = (const float*)d_in[idx++];
    const float* dW2   = (const float*)d_in[idx++];
    const float* dB2   = (const float*)d_in[idx++];
    const float* dLn1g = (const float*)d_in[idx++];
    const float* dLn1b = (const float*)d_in[idx++];
    const float* dLn2g = (const float*)d_in[idx++];
    const float* dLn2b = (const float*)d_in[idx++];
    const float* dLn3g = (const float*)d_in[idx++];
    const float* dLn3b = (const float*)d_in[idx++];

    float* ws = (float*)d_ws;
    u16* OV    = (u16*)ws;
    u16* QKVb  = OV;
    u16* H1b   = OV;
    u16* CKVb  = OV;
    u16* AFb    = (u16*)(ws + 8388608);
    float* Dpart = ws + 8388608;
    float* X1   = ws + 10485760;
    float* XOUT = ws + 14680064;
    float* SuffV = ws + 18874368;
    float* Opart = ws + 18874368;
    float* DA    = ws + 20103168;
    float* Y1   = ws + 20512768;
    float* Y2   = ws + 20922368;
    float* YOUT = ws + 21331968;
    u16* ub  = (u16*)(ws + 21741568);
    u16* XBc = ub;
    u16* YB  = ub + 4194304;
    u16* Y1b = ub + 4603904;
    u16* Y2b = ub + 5013504;
    u16* DQb = ub + 5423104;
    u16* DAb = ub + 5832704;
    u16* DHb = ub + 6242304;
    u16* DQKVb = DHb;
    u16* WB  = ub + 7880704;

    const unsigned eQKVT = 0, eW1T = 1572864, eW2T = 3670016,
                   dQKV1T = 5767168, dWq2T = 7340032, dKV2T = 7864320,
                   dW1T = 8912896, dW2T = 11010048;

    auto gemm = [&](const u16* A, const u16* Bt, const float* bias, float* Cf, u16* Cb,
                    int M, int K, int N, int relu) {
        dim3 grid(N / 128, (M + 127) / 128);
        hipLaunchKernelGGL(gemm_mfma_kernel, grid, dim3(256), 0, stream,
                           A, Bt, bias, Cf, Cb, M, K, N, relu);
    };
    auto gemm64 = [&](const u16* A, const u16* Bt, const float* bias, float* Cf, u16* Cb,
                      int M, int K, int N, int relu) {
        dim3 grid(N / 64, (M + 63) / 64);
        hipLaunchKernelGGL(gemm64_kernel, grid, dim3(256), 0, stream,
                           A, Bt, bias, Cf, Cb, M, K, N, relu);
    };
    auto ln = [&](const float* Xf, const u16* Xb, const float* R, const float* g,
                  const float* bta, float* O, u16* Ob, int rows) {
        hipLaunchKernelGGL(ln_kernel, dim3((rows + 3) / 4), dim3(256), 0, stream,
                           Xf, Xb, R, g, bta, O, Ob, rows);
    };

    // ---- batched weight transposes + input converts ----
    {
        WT9 w9;
        const float* s9[9] = {eWq, eWk, eWv, dWq1, dWk1, dWv1, dWq2, dWk2, dWv2};
        const unsigned d9[9] = {eQKVT, eQKVT + 262144, eQKVT + 524288,
                                dQKV1T, dQKV1T + 262144, dQKV1T + 524288,
                                dWq2T, dKV2T, dKV2T + 262144};
        const unsigned o9[9] = {786432, 786432, 786432, 786432, 786432, 786432,
                                262144, 524288, 524288};
        for (int i = 0; i < 9; ++i) { w9.src[i] = s9[i]; w9.dst[i] = d9[i]; w9.os[i] = o9[i]; }
        hipLaunchKernelGGL(wtrans9_kernel, dim3(16, 16, 18), dim3(256), 0, stream, w9, WB);

        WT4 w4;
        const float* s4[4] = {eW1, eW2, dW1, dW2};
        const unsigned d4[4] = {eW1T, eW2T, dW1T, dW2T};
        const int K4[4] = {512, 2048, 512, 2048};
        const int N4[4] = {2048, 512, 2048, 512};
        for (int i = 0; i < 4; ++i) { w4.src[i] = s4[i]; w4.dst[i] = d4[i]; w4.K[i] = K4[i]; w4.N[i] = N4[i]; }
        hipLaunchKernelGGL(wtrans4_kernel, dim3(64, 64, 8), dim3(256), 0, stream, w4, WB);

        const int n0 = ME * DM, n1 = MD * DM;
        hipLaunchKernelGGL(conv2_kernel, dim3((n0 + n1) / 8 / 256), dim3(256), 0, stream,
                           x0, XBc, n0, y0, YB, n1);
    }

    const int BS = DM;
    const int B1S = DFF;

    // ---------------- encoder ----------------
    const float* xin = x0;
    for (int i = 0; i < L; ++i) {
        gemm(XBc, WB + eQKVT + (size_t)i * 786432, nullptr, nullptr, QKVb, ME, DM, 1536, 0);
        {
            dim3 grid(T_ENC / 128, 8, B);
            hipLaunchKernelGGL(attn_mfma_kernel, grid, dim3(256), 0, stream,
                               QKVb, QKVb + 512, QKVb + 1024, AFb,
                               T_ENC, T_ENC, 1536, 1536, 512);
        }
        ln(nullptr, AFb, xin, eLn1g + i * BS, eLn1b + i * BS, X1, XBc, ME);
        gemm(XBc, WB + eW1T + (size_t)i * 1048576, eB1 + i * B1S, nullptr, H1b, ME, DM, DFF, 1);
        gemm(H1b, WB + eW2T + (size_t)i * 1048576, eB2 + i * BS, nullptr, AFb, ME, DFF, DM, 0);
        ln(nullptr, AFb, X1, eLn2g + i * BS, eLn2b + i * BS, XOUT, XBc, ME);
        xin = XOUT;
    }

    // ---- cross K/V for BOTH decoder layers in one GEMM ----
    gemm(XBc, WB + dKV2T, nullptr, nullptr, CKVb, ME, DM, 2048, 0);

    // ---------------- decoder ----------------
    const float* yin = y0;
    for (int i = 0; i < L; ++i) {
        gemm64(YB, WB + dQKV1T + (size_t)i * 786432, nullptr, nullptr, DQKVb, MD, DM, 1536, 0);
        hipLaunchKernelGGL(suffv_kernel, dim3(B, 8), dim3(64), 0, stream,
                           DQKVb + 1024, SuffV, T_DEC, 1536);
        {
            dim3 grid((T_DEC + 127) / 128, 8, B);
            hipLaunchKernelGGL(attn_causal_kernel, grid, dim3(256), 0, stream,
                               DQKVb, DQKVb + 512, DQKVb + 1024, SuffV, DAb,
                               T_DEC, T_DEC, 1536, 1536, 512);
        }
        ln(nullptr, DAb, yin, dLn1g + i * BS, dLn1b + i * BS, Y1, Y1b, MD);
        gemm64(Y1b, WB + dWq2T + (size_t)i * 262144, nullptr, nullptr, DQb, MD, DM, DM, 0);
        {
            dim3 grid((T_DEC + 63) / 64, 8, B * NSPLIT);
            hipLaunchKernelGGL(attn_split_kernel, grid, dim3(256), 0, stream,
                               DQb, CKVb + (size_t)i * 1024, CKVb + (size_t)i * 1024 + 512,
                               Opart, Dpart, T_DEC, T_ENC, 512, 2048, NSPLIT);
            hipLaunchKernelGGL(combine_ln_kernel, dim3((MD + 3) / 4), dim3(256), 0, stream,
                               Opart, Dpart, NSPLIT, MD,
                               Y1, dLn2g + i * BS, dLn2b + i * BS, Y2, Y2b);
        }
        gemm64(Y2b, WB + dW1T + (size_t)i * 1048576, dB1 + i * B1S, nullptr, DHb, MD, DM, DFF, 1);
        gemm64(DHb, WB + dW2T + (size_t)i * 1048576, dB2 + i * BS, DA, nullptr, MD, DFF, DM, 0);
        float* yout = (i == L - 1) ? (float*)d_out : YOUT;
        ln(DA, nullptr, Y2, dLn3g + i * BS, dLn3b + i * BS, yout,
           (i == L - 1) ? nullptr : YB, MD);
        yin = yout;
    }
}

// Round 9
// 830.654 us; speedup vs baseline: 1.0391x; 1.0391x over previous
//
#include <hip/hip_runtime.h>
#include <cstddef>

typedef unsigned short u16;
typedef __attribute__((ext_vector_type(8))) short bf16x8;   // 8 bf16 = 4 VGPRs
typedef __attribute__((ext_vector_type(4))) float f32x4;    // MFMA 16x16 accumulator

__device__ __forceinline__ u16 f2b(float f) {
    union { float f; unsigned u; } x; x.f = f;
    unsigned r = x.u + 0x7FFFu + ((x.u >> 16) & 1u);   // round-to-nearest-even
    return (u16)(r >> 16);
}
__device__ __forceinline__ float b2f(u16 v) {
    union { unsigned u; float f; } x; x.u = ((unsigned)v) << 16;
    return x.f;
}

__device__ __forceinline__ void gload_lds16(const u16* g, u16* l) {
    __builtin_amdgcn_global_load_lds(
        (const __attribute__((address_space(1))) void*)g,
        (__attribute__((address_space(3))) void*)l, 16, 0, 0);
}

// ---------------------------------------------------------------------------
// bf16 MFMA GEMM, double-buffered LDS pipeline (AITER/m139 pattern):
// 128x128 tile, BK=32, two 16 KB LDS buffers. Per iter: raw s_barrier ->
// issue tile t+1 loads (other buffer) -> s_waitcnt vmcnt(4) (tile-t loads,
// issued one full compute ago) -> s_barrier -> 16 MFMA. The vmcnt(4) wait is
// ~free because the loads overlapped the previous iteration's MFMA block --
// unlike __syncthreads' vmcnt(0) drain which stalls the full HBM latency.
// Output fp32 (Cf) or bf16 (Cb). Requires K%32==0, N%128==0; M ragged.
// ---------------------------------------------------------------------------
__global__ __launch_bounds__(256) void gemm_mfma_kernel(
    const u16* __restrict__ A, const u16* __restrict__ Bt,
    const float* __restrict__ bias,
    float* __restrict__ Cf, u16* __restrict__ Cb,
    int M, int K, int N, int relu)
{
    __shared__ __align__(16) u16 As[2][128 * 32];
    __shared__ __align__(16) u16 Bs[2][128 * 32];

    const int tid  = threadIdx.x;
    const int wave = tid >> 6;
    const int lane = tid & 63;
    const int m0 = blockIdx.y * 128;
    const int n0 = blockIdx.x * 128;

    const int wm = (wave & 1) * 64;
    const int wn = (wave >> 1) * 64;

    const int srow  = lane >> 2;        // 0..15
    const int skoff = (lane & 3) * 8;   // 0,8,16,24

    // staging rows for this thread (clamped once; K-offset varies)
    const int r0 = wave * 32;
    int gr0 = m0 + r0 + srow;       if (gr0 >= M) gr0 = M - 1;
    int gr1 = m0 + r0 + 16 + srow;  if (gr1 >= M) gr1 = M - 1;
    const u16* a0 = A + (size_t)gr0 * K + skoff;
    const u16* a1 = A + (size_t)gr1 * K + skoff;
    const u16* b0p = Bt + (size_t)(n0 + r0 + srow) * K + skoff;
    const u16* b1p = Bt + (size_t)(n0 + r0 + 16 + srow) * K + skoff;

    f32x4 acc[4][4];
#pragma unroll
    for (int i = 0; i < 4; ++i)
#pragma unroll
        for (int j = 0; j < 4; ++j)
            acc[i][j] = (f32x4){0.f, 0.f, 0.f, 0.f};

    const int fm = lane & 15;
    const int fk = (lane >> 4) * 8;

    const int NK = K >> 5;

    // prologue: tile 0 -> buffer 0
    gload_lds16(a0, &As[0][(r0) * 32]);
    gload_lds16(a1, &As[0][(r0 + 16) * 32]);
    gload_lds16(b0p, &Bs[0][(r0) * 32]);
    gload_lds16(b1p, &Bs[0][(r0 + 16) * 32]);

    for (int t = 0; t < NK; ++t) {
        const int cur = t & 1;
        // all waves done reading buf[!cur] (tile t-1's compute + its ds_reads)
        __asm__ volatile("s_waitcnt lgkmcnt(0)" ::: "memory");
        __builtin_amdgcn_s_barrier();
        if (t + 1 < NK) {
            const int nxt = (t + 1) & 1;
            const int ko = (t + 1) << 5;
            gload_lds16(a0 + ko, &As[nxt][(r0) * 32]);
            gload_lds16(a1 + ko, &As[nxt][(r0 + 16) * 32]);
            gload_lds16(b0p + ko, &Bs[nxt][(r0) * 32]);
            gload_lds16(b1p + ko, &Bs[nxt][(r0 + 16) * 32]);
            __asm__ volatile("s_waitcnt vmcnt(4)" ::: "memory");
        } else {
            __asm__ volatile("s_waitcnt vmcnt(0)" ::: "memory");
        }
        __builtin_amdgcn_s_barrier();   // tile-t data visible to all waves

        bf16x8 af[4], bfr[4];
#pragma unroll
        for (int u = 0; u < 4; ++u) {
            af[u]  = *(const bf16x8*)(&As[cur][(wm + u * 16 + fm) * 32 + fk]);
            bfr[u] = *(const bf16x8*)(&Bs[cur][(wn + u * 16 + fm) * 32 + fk]);
        }
#pragma unroll
        for (int i = 0; i < 4; ++i)
#pragma unroll
            for (int j = 0; j < 4; ++j)
                acc[i][j] = __builtin_amdgcn_mfma_f32_16x16x32_bf16(
                    af[i], bfr[j], acc[i][j], 0, 0, 0);
    }

    const int col = lane & 15;
    const int rq  = (lane >> 4) * 4;
#pragma unroll
    for (int j = 0; j < 4; ++j) {
        const int gn = n0 + wn + j * 16 + col;
        const float bb = bias ? bias[gn] : 0.f;
#pragma unroll
        for (int i = 0; i < 4; ++i) {
            const int gmb = m0 + wm + i * 16 + rq;
#pragma unroll
            for (int r = 0; r < 4; ++r) {
                const int gm = gmb + r;
                if (gm < M) {
                    float v = acc[i][j][r] + bb;
                    if (relu) v = fmaxf(v, 0.f);
                    if (Cb) Cb[(size_t)gm * N + gn] = f2b(v);
                    else    Cf[(size_t)gm * N + gn] = v;
                }
            }
        }
    }
}

// ---------------------------------------------------------------------------
// Small-tile bf16 MFMA GEMM (decoder), same double-buffer pipeline:
// 64x64 tile, BK=32, two 8 KB LDS buffers, prefetch=2 loads/thread.
// ---------------------------------------------------------------------------
__global__ __launch_bounds__(256) void gemm64_kernel(
    const u16* __restrict__ A, const u16* __restrict__ Bt,
    const float* __restrict__ bias,
    float* __restrict__ Cf, u16* __restrict__ Cb,
    int M, int K, int N, int relu)
{
    __shared__ __align__(16) u16 As[2][64 * 32];
    __shared__ __align__(16) u16 Bs[2][64 * 32];

    const int tid  = threadIdx.x;
    const int wave = tid >> 6;
    const int lane = tid & 63;
    const int m0 = blockIdx.y * 64;
    const int n0 = blockIdx.x * 64;
    const int wm = (wave & 1) * 32;
    const int wn = (wave >> 1) * 32;

    const int srow  = lane >> 2;        // 0..15
    const int skoff = (lane & 3) * 8;

    int gr = m0 + wave * 16 + srow; if (gr >= M) gr = M - 1;
    const u16* ap = A + (size_t)gr * K + skoff;
    const u16* bp = Bt + (size_t)(n0 + wave * 16 + srow) * K + skoff;

    f32x4 acc[2][2];
#pragma unroll
    for (int i = 0; i < 2; ++i)
#pragma unroll
        for (int j = 0; j < 2; ++j) acc[i][j] = (f32x4){0.f, 0.f, 0.f, 0.f};

    const int fm = lane & 15;
    const int fk = (lane >> 4) * 8;

    const int NK = K >> 5;

    gload_lds16(ap, &As[0][(wave * 16) * 32]);
    gload_lds16(bp, &Bs[0][(wave * 16) * 32]);

    for (int t = 0; t < NK; ++t) {
        const int cur = t & 1;
        __asm__ volatile("s_waitcnt lgkmcnt(0)" ::: "memory");
        __builtin_amdgcn_s_barrier();
        if (t + 1 < NK) {
            const int nxt = (t + 1) & 1;
            const int ko = (t + 1) << 5;
            gload_lds16(ap + ko, &As[nxt][(wave * 16) * 32]);
            gload_lds16(bp + ko, &Bs[nxt][(wave * 16) * 32]);
            __asm__ volatile("s_waitcnt vmcnt(2)" ::: "memory");
        } else {
            __asm__ volatile("s_waitcnt vmcnt(0)" ::: "memory");
        }
        __builtin_amdgcn_s_barrier();

        bf16x8 af[2], bfr[2];
#pragma unroll
        for (int u = 0; u < 2; ++u) {
            af[u]  = *(const bf16x8*)(&As[cur][(wm + u * 16 + fm) * 32 + fk]);
            bfr[u] = *(const bf16x8*)(&Bs[cur][(wn + u * 16 + fm) * 32 + fk]);
        }
#pragma unroll
        for (int i = 0; i < 2; ++i)
#pragma unroll
            for (int j = 0; j < 2; ++j)
                acc[i][j] = __builtin_amdgcn_mfma_f32_16x16x32_bf16(
                    af[i], bfr[j], acc[i][j], 0, 0, 0);
    }

    const int col = lane & 15;
    const int rq  = (lane >> 4) * 4;
#pragma unroll
    for (int j = 0; j < 2; ++j) {
        const int gn = n0 + wn + j * 16 + col;
        const float bb = bias ? bias[gn] : 0.f;
#pragma unroll
        for (int i = 0; i < 2; ++i) {
            const int gmb = m0 + wm + i * 16 + rq;
#pragma unroll
            for (int r = 0; r < 4; ++r) {
                const int gm = gmb + r;
                if (gm < M) {
                    float v = acc[i][j][r] + bb;
                    if (relu) v = fmaxf(v, 0.f);
                    if (Cb) Cb[(size_t)gm * N + gn] = f2b(v);
                    else    Cf[(size_t)gm * N + gn] = v;
                }
            }
        }
    }
}

// ---------------------------------------------------------------------------
// bf16 MFMA flash attention, q-tile 128, k-tile 128, NO-RESCALE softmax
// (O(1) scores). LDS: Ks[128][72] + Vs[64][144] + Ps[128][144] = 73.7 KB.
// Requires Lk%128==0; Lq ragged.
// ---------------------------------------------------------------------------
__global__ __launch_bounds__(256) void attn_mfma_kernel(
    const u16* __restrict__ Qp, const u16* __restrict__ Kp,
    const u16* __restrict__ Vp, u16* __restrict__ Op,
    int Lq, int Lk, int ldq, int ldkv, int ldo)
{
    const int q0 = blockIdx.x * 128;
    const int h  = blockIdx.y;
    const int b  = blockIdx.z;
    const int tid  = threadIdx.x;
    const int wave = tid >> 6;
    const int lane = tid & 63;
    const int c = lane & 15;
    const int g = lane >> 4;
    const float scale = 0.125f;

    __shared__ __align__(16) u16 Ks[128 * 72];    // [k][d]
    __shared__ __align__(16) u16 Vs[64 * 144];    // transposed: [d][k], k=0..127
    __shared__ __align__(16) u16 Ps[128 * 144];   // [q][k], k=0..127

    bf16x8 aq[2][2];
#pragma unroll
    for (int half = 0; half < 2; ++half) {
        int qrow = q0 + wave * 32 + half * 16 + c;
        if (qrow > Lq - 1) qrow = Lq - 1;
        const u16* src = Qp + ((size_t)(b * Lq + qrow)) * ldq + h * 64 + g * 8;
        aq[half][0] = *(const bf16x8*)(src);
        aq[half][1] = *(const bf16x8*)(src + 32);
    }

    float den[2][4] = {};
    f32x4 o[2][4];
#pragma unroll
    for (int half = 0; half < 2; ++half)
#pragma unroll
        for (int j = 0; j < 4; ++j) o[half][j] = (f32x4){0.f, 0.f, 0.f, 0.f};

    const int srow = tid & 63;
    const int sseg = tid >> 6;

    for (int t = 0; t < (Lk >> 7); ++t) {
        const int k0 = t << 7;
        __syncthreads();
#pragma unroll
        for (int sub = 0; sub < 2; ++sub) {
            const int kr = k0 + sub * 64 + srow;
            const u16* kg = Kp + ((size_t)(b * Lk + kr)) * ldkv + h * 64;
            *(bf16x8*)(&Ks[(sub * 64 + srow) * 72 + sseg * 8])      = *(const bf16x8*)(kg + sseg * 8);
            *(bf16x8*)(&Ks[(sub * 64 + srow) * 72 + 32 + sseg * 8]) = *(const bf16x8*)(kg + 32 + sseg * 8);
            const u16* vg = Vp + ((size_t)(b * Lk + kr)) * ldkv + h * 64;
            bf16x8 v0 = *(const bf16x8*)(vg + sseg * 8);
            bf16x8 v1 = *(const bf16x8*)(vg + 32 + sseg * 8);
#pragma unroll
            for (int i = 0; i < 8; ++i) {
                Vs[(sseg * 8 + i) * 144 + sub * 64 + srow]      = (u16)v0[i];
                Vs[(32 + sseg * 8 + i) * 144 + sub * 64 + srow] = (u16)v1[i];
            }
        }
        __syncthreads();

#pragma unroll
        for (int half = 0; half < 2; ++half) {
            f32x4 s[8];
#pragma unroll
            for (int jn = 0; jn < 8; ++jn) s[jn] = (f32x4){0.f, 0.f, 0.f, 0.f};
#pragma unroll
            for (int jn = 0; jn < 8; ++jn) {
                bf16x8 b0 = *(const bf16x8*)(&Ks[(jn * 16 + c) * 72 + g * 8]);
                bf16x8 b1 = *(const bf16x8*)(&Ks[(jn * 16 + c) * 72 + 32 + g * 8]);
                s[jn] = __builtin_amdgcn_mfma_f32_16x16x32_bf16(aq[half][0], b0, s[jn], 0, 0, 0);
                s[jn] = __builtin_amdgcn_mfma_f32_16x16x32_bf16(aq[half][1], b1, s[jn], 0, 0, 0);
            }
#pragma unroll
            for (int jn = 0; jn < 8; ++jn)
#pragma unroll
                for (int r = 0; r < 4; ++r) {
                    const float p = __expf(s[jn][r] * scale);
                    den[half][r] += p;
                    Ps[(wave * 32 + half * 16 + g * 4 + r) * 144 + jn * 16 + c] = f2b(p);
                }
        }

        __asm__ volatile("s_waitcnt lgkmcnt(0)" ::: "memory");   // in-wave Ps order

#pragma unroll
        for (int half = 0; half < 2; ++half) {
            const int qr = (wave * 32 + half * 16 + c) * 144;
#pragma unroll
            for (int sub = 0; sub < 2; ++sub) {
                bf16x8 ap0 = *(const bf16x8*)(&Ps[qr + sub * 64 + g * 8]);
                bf16x8 ap1 = *(const bf16x8*)(&Ps[qr + sub * 64 + 32 + g * 8]);
#pragma unroll
                for (int jd = 0; jd < 4; ++jd) {
                    bf16x8 b0 = *(const bf16x8*)(&Vs[(jd * 16 + c) * 144 + sub * 64 + g * 8]);
                    bf16x8 b1 = *(const bf16x8*)(&Vs[(jd * 16 + c) * 144 + sub * 64 + 32 + g * 8]);
                    o[half][jd] = __builtin_amdgcn_mfma_f32_16x16x32_bf16(ap0, b0, o[half][jd], 0, 0, 0);
                    o[half][jd] = __builtin_amdgcn_mfma_f32_16x16x32_bf16(ap1, b1, o[half][jd], 0, 0, 0);
                }
            }
        }
    }

#pragma unroll
    for (int half = 0; half < 2; ++half)
#pragma unroll
        for (int r = 0; r < 4; ++r) {
#pragma unroll
            for (int msk = 1; msk < 16; msk <<= 1)
                den[half][r] += __shfl_xor(den[half][r], msk, 64);
        }

#pragma unroll
    for (int half = 0; half < 2; ++half)
#pragma unroll
        for (int r = 0; r < 4; ++r) {
            const int q = q0 + wave * 32 + half * 16 + g * 4 + r;
            if (q < Lq) {
                const float inv = 1.0f / den[half][r];
#pragma unroll
                for (int jd = 0; jd < 4; ++jd)
                    Op[((size_t)(b * Lq + q)) * ldo + h * 64 + jd * 16 + c] =
                        f2b(o[half][jd][r] * inv);
            }
        }
}

// ---------------------------------------------------------------------------
// CAUSAL (post-softmax -1e10 fill) MFMA attention:
//   O[q] = (sum_{k<=q} e_k V_k)/den + (-1e10)*suffV[q], den over all k<Lk.
// ---------------------------------------------------------------------------
__global__ __launch_bounds__(256) void attn_causal_kernel(
    const u16* __restrict__ Qp, const u16* __restrict__ Kp,
    const u16* __restrict__ Vp, const float* __restrict__ SuffV,
    u16* __restrict__ Op,
    int Lq, int Lk, int ldq, int ldkv, int ldo)
{
    const int q0 = blockIdx.x * 128;
    const int h  = blockIdx.y;
    const int b  = blockIdx.z;
    const int tid  = threadIdx.x;
    const int wave = tid >> 6;
    const int lane = tid & 63;
    const int c = lane & 15;
    const int g = lane >> 4;
    const float scale = 0.125f;

    __shared__ __align__(16) u16 Ks[64 * 72];
    __shared__ __align__(16) u16 Vs[64 * 72];
    __shared__ __align__(16) u16 Ps[128 * 72];

    bf16x8 aq[2][2];
#pragma unroll
    for (int half = 0; half < 2; ++half) {
        int qrow = q0 + wave * 32 + half * 16 + c;
        if (qrow > Lq - 1) qrow = Lq - 1;
        const u16* src = Qp + ((size_t)(b * Lq + qrow)) * ldq + h * 64 + g * 8;
        aq[half][0] = *(const bf16x8*)(src);
        aq[half][1] = *(const bf16x8*)(src + 32);
    }

    float den[2][4] = {};
    f32x4 o[2][4];
#pragma unroll
    for (int half = 0; half < 2; ++half)
#pragma unroll
        for (int j = 0; j < 4; ++j) o[half][j] = (f32x4){0.f, 0.f, 0.f, 0.f};

    const int srow = tid & 63;
    const int sseg = tid >> 6;
    const int ntiles = (Lk + 63) >> 6;

    for (int t = 0; t < ntiles; ++t) {
        const int k0 = t << 6;
        __syncthreads();
        {
            int kr = k0 + srow; if (kr > Lk - 1) kr = Lk - 1;
            const u16* kg = Kp + ((size_t)(b * Lk + kr)) * ldkv + h * 64;
            *(bf16x8*)(&Ks[srow * 72 + sseg * 8])      = *(const bf16x8*)(kg + sseg * 8);
            *(bf16x8*)(&Ks[srow * 72 + 32 + sseg * 8]) = *(const bf16x8*)(kg + 32 + sseg * 8);
            const u16* vg = Vp + ((size_t)(b * Lk + kr)) * ldkv + h * 64;
            bf16x8 v0 = *(const bf16x8*)(vg + sseg * 8);
            bf16x8 v1 = *(const bf16x8*)(vg + 32 + sseg * 8);
#pragma unroll
            for (int i = 0; i < 8; ++i) {
                Vs[(sseg * 8 + i) * 72 + srow]      = (u16)v0[i];
                Vs[(32 + sseg * 8 + i) * 72 + srow] = (u16)v1[i];
            }
        }
        __syncthreads();

#pragma unroll
        for (int half = 0; half < 2; ++half) {
            f32x4 s[4];
#pragma unroll
            for (int jn = 0; jn < 4; ++jn) s[jn] = (f32x4){0.f, 0.f, 0.f, 0.f};
#pragma unroll
            for (int jn = 0; jn < 4; ++jn) {
                bf16x8 b0 = *(const bf16x8*)(&Ks[(jn * 16 + c) * 72 + g * 8]);
                bf16x8 b1 = *(const bf16x8*)(&Ks[(jn * 16 + c) * 72 + 32 + g * 8]);
                s[jn] = __builtin_amdgcn_mfma_f32_16x16x32_bf16(aq[half][0], b0, s[jn], 0, 0, 0);
                s[jn] = __builtin_amdgcn_mfma_f32_16x16x32_bf16(aq[half][1], b1, s[jn], 0, 0, 0);
            }
#pragma unroll
            for (int jn = 0; jn < 4; ++jn)
#pragma unroll
                for (int r = 0; r < 4; ++r) {
                    const int kcol = k0 + jn * 16 + c;
                    const int qrow = q0 + wave * 32 + half * 16 + g * 4 + r;
                    const float e = __expf(s[jn][r] * scale);
                    const float ev = (kcol < Lk) ? e : 0.f;
                    den[half][r] += ev;
                    const float pv = (kcol <= qrow) ? ev : 0.f;
                    Ps[(wave * 32 + half * 16 + g * 4 + r) * 72 + jn * 16 + c] = f2b(pv);
                }
        }

        __asm__ volatile("s_waitcnt lgkmcnt(0)" ::: "memory");

#pragma unroll
        for (int half = 0; half < 2; ++half) {
            bf16x8 ap0 = *(const bf16x8*)(&Ps[(wave * 32 + half * 16 + c) * 72 + g * 8]);
            bf16x8 ap1 = *(const bf16x8*)(&Ps[(wave * 32 + half * 16 + c) * 72 + 32 + g * 8]);
#pragma unroll
            for (int jd = 0; jd < 4; ++jd) {
                bf16x8 b0 = *(const bf16x8*)(&Vs[(jd * 16 + c) * 72 + g * 8]);
                bf16x8 b1 = *(const bf16x8*)(&Vs[(jd * 16 + c) * 72 + 32 + g * 8]);
                o[half][jd] = __builtin_amdgcn_mfma_f32_16x16x32_bf16(ap0, b0, o[half][jd], 0, 0, 0);
                o[half][jd] = __builtin_amdgcn_mfma_f32_16x16x32_bf16(ap1, b1, o[half][jd], 0, 0, 0);
            }
        }
    }

#pragma unroll
    for (int half = 0; half < 2; ++half)
#pragma unroll
        for (int r = 0; r < 4; ++r) {
#pragma unroll
            for (int msk = 1; msk < 16; msk <<= 1)
                den[half][r] += __shfl_xor(den[half][r], msk, 64);
        }

#pragma unroll
    for (int half = 0; half < 2; ++half)
#pragma unroll
        for (int r = 0; r < 4; ++r) {
            const int q = q0 + wave * 32 + half * 16 + g * 4 + r;
            if (q < Lq) {
                const float inv = 1.0f / den[half][r];
                const float* sv = SuffV + ((size_t)(b * Lq + q)) * 512 + h * 64;
#pragma unroll
                for (int jd = 0; jd < 4; ++jd)
                    Op[((size_t)(b * Lq + q)) * ldo + h * 64 + jd * 16 + c] =
                        f2b(o[half][jd][r] * inv - 1.0e10f * sv[jd * 16 + c]);
            }
        }
}

// Suffix-sum of V rows (exclusive): SuffV[b][q][h*64+d] = sum_{k>q} V[b][k][...]
__global__ __launch_bounds__(64) void suffv_kernel(
    const u16* __restrict__ Vp, float* __restrict__ SuffV, int Lq, int ldv)
{
    const int b = blockIdx.x;
    const int h = blockIdx.y;
    const int d = threadIdx.x;
    float acc = 0.f;
    for (int q = Lq - 1; q >= 0; --q) {
        SuffV[((size_t)(b * Lq + q)) * 512 + h * 64 + d] = acc;
        acc += b2f(Vp[((size_t)(b * Lq + q)) * ldv + h * 64 + d]);
    }
}

// ---------------------------------------------------------------------------
// Split-K cross attention (q-tile 64): partial unnormalized O + partial den.
// ---------------------------------------------------------------------------
__global__ __launch_bounds__(256) void attn_split_kernel(
    const u16* __restrict__ Qp, const u16* __restrict__ Kp,
    const u16* __restrict__ Vp, float* __restrict__ Opart,
    float* __restrict__ Dpart,
    int Lq, int Lk, int ldq, int ldkv, int nsplit)
{
    const int q0 = blockIdx.x * 64;
    const int h  = blockIdx.y;
    const int b  = blockIdx.z / nsplit;
    const int sp = blockIdx.z % nsplit;
    const int tid  = threadIdx.x;
    const int wave = tid >> 6;
    const int lane = tid & 63;
    const int c = lane & 15;
    const int g = lane >> 4;
    const float scale = 0.125f;
    const int rowsTot = gridDim.z / nsplit * Lq;   // B*Lq

    __shared__ __align__(16) u16 Ks[64 * 72];
    __shared__ __align__(16) u16 Vs[64 * 72];
    __shared__ __align__(16) u16 Ps[64 * 72];

    bf16x8 aq[2];
    {
        int qrow = q0 + wave * 16 + c;
        if (qrow > Lq - 1) qrow = Lq - 1;
        const u16* src = Qp + ((size_t)(b * Lq + qrow)) * ldq + h * 64 + g * 8;
        aq[0] = *(const bf16x8*)(src);
        aq[1] = *(const bf16x8*)(src + 32);
    }

    float den[4] = {0.f, 0.f, 0.f, 0.f};
    f32x4 o[4];
#pragma unroll
    for (int j = 0; j < 4; ++j) o[j] = (f32x4){0.f, 0.f, 0.f, 0.f};

    const int srow = tid & 63;
    const int sseg = tid >> 6;
    const int ntile = (Lk >> 6) / nsplit;

    for (int t = sp * ntile; t < (sp + 1) * ntile; ++t) {
        const int k0 = t << 6;
        __syncthreads();
        {
            const u16* kg = Kp + ((size_t)(b * Lk + k0 + srow)) * ldkv + h * 64;
            *(bf16x8*)(&Ks[srow * 72 + sseg * 8])      = *(const bf16x8*)(kg + sseg * 8);
            *(bf16x8*)(&Ks[srow * 72 + 32 + sseg * 8]) = *(const bf16x8*)(kg + 32 + sseg * 8);
            const u16* vg = Vp + ((size_t)(b * Lk + k0 + srow)) * ldkv + h * 64;
            bf16x8 v0 = *(const bf16x8*)(vg + sseg * 8);
            bf16x8 v1 = *(const bf16x8*)(vg + 32 + sseg * 8);
#pragma unroll
            for (int i = 0; i < 8; ++i) {
                Vs[(sseg * 8 + i) * 72 + srow]      = (u16)v0[i];
                Vs[(32 + sseg * 8 + i) * 72 + srow] = (u16)v1[i];
            }
        }
        __syncthreads();

        f32x4 s[4];
#pragma unroll
        for (int jn = 0; jn < 4; ++jn) s[jn] = (f32x4){0.f, 0.f, 0.f, 0.f};
#pragma unroll
        for (int jn = 0; jn < 4; ++jn) {
            bf16x8 b0 = *(const bf16x8*)(&Ks[(jn * 16 + c) * 72 + g * 8]);
            bf16x8 b1 = *(const bf16x8*)(&Ks[(jn * 16 + c) * 72 + 32 + g * 8]);
            s[jn] = __builtin_amdgcn_mfma_f32_16x16x32_bf16(aq[0], b0, s[jn], 0, 0, 0);
            s[jn] = __builtin_amdgcn_mfma_f32_16x16x32_bf16(aq[1], b1, s[jn], 0, 0, 0);
        }
#pragma unroll
        for (int jn = 0; jn < 4; ++jn)
#pragma unroll
            for (int r = 0; r < 4; ++r) {
                const float p = __expf(s[jn][r] * scale);
                den[r] += p;
                Ps[(wave * 16 + g * 4 + r) * 72 + jn * 16 + c] = f2b(p);
            }

        __asm__ volatile("s_waitcnt lgkmcnt(0)" ::: "memory");

        bf16x8 ap0 = *(const bf16x8*)(&Ps[(wave * 16 + c) * 72 + g * 8]);
        bf16x8 ap1 = *(const bf16x8*)(&Ps[(wave * 16 + c) * 72 + 32 + g * 8]);
#pragma unroll
        for (int jd = 0; jd < 4; ++jd) {
            bf16x8 b0 = *(const bf16x8*)(&Vs[(jd * 16 + c) * 72 + g * 8]);
            bf16x8 b1 = *(const bf16x8*)(&Vs[(jd * 16 + c) * 72 + 32 + g * 8]);
            o[jd] = __builtin_amdgcn_mfma_f32_16x16x32_bf16(ap0, b0, o[jd], 0, 0, 0);
            o[jd] = __builtin_amdgcn_mfma_f32_16x16x32_bf16(ap1, b1, o[jd], 0, 0, 0);
        }
    }

#pragma unroll
    for (int r = 0; r < 4; ++r) {
#pragma unroll
        for (int msk = 1; msk < 16; msk <<= 1)
            den[r] += __shfl_xor(den[r], msk, 64);
    }

#pragma unroll
    for (int r = 0; r < 4; ++r) {
        const int q = q0 + wave * 16 + g * 4 + r;
        if (q < Lq) {
            const size_t prow = (size_t)sp * rowsTot + b * Lq + q;
#pragma unroll
            for (int jd = 0; jd < 4; ++jd)
                Opart[prow * 512 + h * 64 + jd * 16 + c] = o[jd][r];
            if (c == 0) Dpart[prow * 8 + h] = den[r];
        }
    }
}

// ---------------------------------------------------------------------------
// Fused combine + residual + LayerNorm.
// ---------------------------------------------------------------------------
__global__ __launch_bounds__(256) void combine_ln_kernel(
    const float* __restrict__ Opart, const float* __restrict__ Dpart,
    int nsplit, int nrows,
    const float* __restrict__ R,
    const float* __restrict__ g, const float* __restrict__ beta,
    float* __restrict__ O, u16* __restrict__ Ob)
{
    const int row = blockIdx.x * 4 + (threadIdx.x >> 6);
    const int lane = threadIdx.x & 63;
    if (row >= nrows) return;
    const size_t base = (size_t)row * 512 + lane * 8;
    const int h = lane >> 3;

    float sd = 0.f;
    float v[8] = {};
    for (int s = 0; s < nsplit; ++s) {
        sd += Dpart[((size_t)s * nrows + row) * 8 + h];
        const float* op = Opart + ((size_t)s * nrows + row) * 512 + lane * 8;
        float4 a = *(const float4*)(op);
        float4 b = *(const float4*)(op + 4);
        v[0] += a.x; v[1] += a.y; v[2] += a.z; v[3] += a.w;
        v[4] += b.x; v[5] += b.y; v[6] += b.z; v[7] += b.w;
    }
    const float invd = 1.0f / sd;
    {
        float4 a = *(const float4*)(R + base);
        float4 b = *(const float4*)(R + base + 4);
        v[0] = v[0] * invd + a.x; v[1] = v[1] * invd + a.y;
        v[2] = v[2] * invd + a.z; v[3] = v[3] * invd + a.w;
        v[4] = v[4] * invd + b.x; v[5] = v[5] * invd + b.y;
        v[6] = v[6] * invd + b.z; v[7] = v[7] * invd + b.w;
    }

    float sum = 0.f;
#pragma unroll
    for (int i = 0; i < 8; ++i) sum += v[i];
#pragma unroll
    for (int msk = 1; msk < 64; msk <<= 1) sum += __shfl_xor(sum, msk, 64);
    const float mean = sum * (1.0f / 512.0f);

    float var = 0.f;
#pragma unroll
    for (int i = 0; i < 8; ++i) { v[i] -= mean; var += v[i] * v[i]; }
#pragma unroll
    for (int msk = 1; msk < 64; msk <<= 1) var += __shfl_xor(var, msk, 64);
    const float rstd = rsqrtf(var * (1.0f / 512.0f) + 1e-5f);

    float o[8];
#pragma unroll
    for (int i = 0; i < 8; ++i)
        o[i] = v[i] * rstd * g[lane * 8 + i] + beta[lane * 8 + i];

    *(float4*)(O + base)     = make_float4(o[0], o[1], o[2], o[3]);
    *(float4*)(O + base + 4) = make_float4(o[4], o[5], o[6], o[7]);
    if (Ob) {
        bf16x8 ob;
#pragma unroll
        for (int i = 0; i < 8; ++i) ob[i] = (short)f2b(o[i]);
        *(bf16x8*)(Ob + base) = ob;
    }
}

// ---------------------------------------------------------------------------
// Batched weight transpose+convert.
// ---------------------------------------------------------------------------
struct WT9 { const float* src[9]; unsigned dst[9]; unsigned os[9]; };
struct WT4 { const float* src[4]; unsigned dst[4]; int K[4]; int N[4]; };

__device__ __forceinline__ void wtrans_tile(
    const float* Wl, u16* Wtl, int K, int N, int k0, int n0, int tid)
{
    __shared__ float t[32][33];
    const int tr = tid >> 3;
    const int tc = (tid & 7) * 4;
    float4 v = *(const float4*)(Wl + (size_t)(k0 + tr) * N + n0 + tc);
    t[tr][tc] = v.x; t[tr][tc + 1] = v.y; t[tr][tc + 2] = v.z; t[tr][tc + 3] = v.w;
    __syncthreads();
    ushort4 o;
    o.x = f2b(t[tc + 0][tr]); o.y = f2b(t[tc + 1][tr]);
    o.z = f2b(t[tc + 2][tr]); o.w = f2b(t[tc + 3][tr]);
    *(ushort4*)(Wtl + (size_t)(n0 + tr) * K + k0 + tc) = o;
}

__global__ __launch_bounds__(256) void wtrans9_kernel(WT9 d, u16* __restrict__ WB)
{
    const int w = blockIdx.z >> 1;
    const int layer = blockIdx.z & 1;
    const float* Wl = d.src[w] + (size_t)layer * 512 * 512;
    u16* Wtl = WB + d.dst[w] + (size_t)layer * d.os[w];
    wtrans_tile(Wl, Wtl, 512, 512, blockIdx.y * 32, blockIdx.x * 32, threadIdx.x);
}

__global__ __launch_bounds__(256) void wtrans4_kernel(WT4 d, u16* __restrict__ WB)
{
    const int w = blockIdx.z >> 1;
    const int layer = blockIdx.z & 1;
    const int K = d.K[w], N = d.N[w];
    const int k0 = blockIdx.y * 32, n0 = blockIdx.x * 32;
    if (k0 >= K || n0 >= N) return;
    const float* Wl = d.src[w] + (size_t)layer * K * N;
    u16* Wtl = WB + d.dst[w] + (size_t)layer * 1048576;
    wtrans_tile(Wl, Wtl, K, N, k0, n0, threadIdx.x);
}

// ---------------------------------------------------------------------------
// fp32 -> bf16 for the two inputs in one launch.
// ---------------------------------------------------------------------------
__global__ __launch_bounds__(256) void conv2_kernel(
    const float* __restrict__ X0, u16* __restrict__ Y0, int n0,
    const float* __restrict__ X1, u16* __restrict__ Y1, int n1)
{
    int i = (blockIdx.x * 256 + threadIdx.x) * 8;
    const float* X; u16* Y;
    if (i < n0) { X = X0 + i; Y = Y0 + i; }
    else if (i < n0 + n1) { X = X1 + (i - n0); Y = Y1 + (i - n0); }
    else return;
    float4 a = *(const float4*)(X);
    float4 b = *(const float4*)(X + 4);
    ushort4 o0, o1;
    o0.x = f2b(a.x); o0.y = f2b(a.y); o0.z = f2b(a.z); o0.w = f2b(a.w);
    o1.x = f2b(b.x); o1.y = f2b(b.y); o1.z = f2b(b.z); o1.w = f2b(b.w);
    *(ushort4*)(Y) = o0;
    *(ushort4*)(Y + 4) = o1;
}

// ---------------------------------------------------------------------------
// Residual + LayerNorm, one wave per row. X fp32 (Xf) or bf16 (Xb).
// ---------------------------------------------------------------------------
__global__ __launch_bounds__(256) void ln_kernel(
    const float* __restrict__ Xf, const u16* __restrict__ Xb,
    const float* __restrict__ R,
    const float* __restrict__ g, const float* __restrict__ beta,
    float* __restrict__ O, u16* __restrict__ Ob, int nrows)
{
    const int row = blockIdx.x * 4 + (threadIdx.x >> 6);
    const int lane = threadIdx.x & 63;
    if (row >= nrows) return;
    const size_t base = (size_t)row * 512 + lane * 8;

    float v[8];
    if (Xf) {
        float4 a = *(const float4*)(Xf + base);
        float4 b = *(const float4*)(Xf + base + 4);
        v[0] = a.x; v[1] = a.y; v[2] = a.z; v[3] = a.w;
        v[4] = b.x; v[5] = b.y; v[6] = b.z; v[7] = b.w;
    } else {
        bf16x8 xb = *(const bf16x8*)(Xb + base);
#pragma unroll
        for (int i = 0; i < 8; ++i) v[i] = b2f((u16)xb[i]);
    }
    {
        float4 a = *(const float4*)(R + base);
        float4 b = *(const float4*)(R + base + 4);
        v[0] += a.x; v[1] += a.y; v[2] += a.z; v[3] += a.w;
        v[4] += b.x; v[5] += b.y; v[6] += b.z; v[7] += b.w;
    }

    float sum = 0.f;
#pragma unroll
    for (int i = 0; i < 8; ++i) sum += v[i];
#pragma unroll
    for (int msk = 1; msk < 64; msk <<= 1) sum += __shfl_xor(sum, msk, 64);
    const float mean = sum * (1.0f / 512.0f);

    float var = 0.f;
#pragma unroll
    for (int i = 0; i < 8; ++i) { v[i] -= mean; var += v[i] * v[i]; }
#pragma unroll
    for (int msk = 1; msk < 64; msk <<= 1) var += __shfl_xor(var, msk, 64);
    const float rstd = rsqrtf(var * (1.0f / 512.0f) + 1e-5f);

    float o[8];
#pragma unroll
    for (int i = 0; i < 8; ++i)
        o[i] = v[i] * rstd * g[lane * 8 + i] + beta[lane * 8 + i];

    *(float4*)(O + base)     = make_float4(o[0], o[1], o[2], o[3]);
    *(float4*)(O + base + 4) = make_float4(o[4], o[5], o[6], o[7]);
    if (Ob) {
        bf16x8 ob;
#pragma unroll
        for (int i = 0; i < 8; ++i) ob[i] = (short)f2b(o[i]);
        *(bf16x8*)(Ob + base) = ob;
    }
}

// ---------------------------------------------------------------------------
// Orchestration
// ---------------------------------------------------------------------------
extern "C" void kernel_launch(void* const* d_in, const int* in_sizes, int n_in,
                              void* d_out, int out_size, void* d_ws, size_t ws_size,
                              hipStream_t stream)
{
    const int B = 8, T_ENC = 1024, T_DEC = 100, DM = 512, DFF = 2048;
    const int ME = B * T_ENC;  // 8192
    const int MD = B * T_DEC;  // 800
    const int L = 2;
    const int NSPLIT = 4;

    int idx = 0;
    const float* x0    = (const float*)d_in[idx++];
    const float* y0    = (const float*)d_in[idx++];
    const float* eWq   = (const float*)d_in[idx++];
    const float* eWk   = (const float*)d_in[idx++];
    const float* eWv   = (const float*)d_in[idx++];
    const float* eW1   = (const float*)d_in[idx++];
    const float* eB1   = (const float*)d_in[idx++];
    const float* eW2   = (const float*)d_in[idx++];
    const float* eB2   = (const float*)d_in[idx++];
    const float* eLn1g = (const float*)d_in[idx++];
    const float* eLn1b = (const float*)d_in[idx++];
    const float* eLn2g = (const float*)d_in[idx++];
    const float* eLn2b = (const float*)d_in[idx++];
    const float* dWq1  = (const float*)d_in[idx++];
    const float* dWk1  = (const float*)d_in[idx++];
    const float* dWv1  = (const float*)d_in[idx++];
    const float* dWq2  = (const float*)d_in[idx++];
    const float* dWk2  = (const float*)d_in[idx++];
    const float* dWv2  = (const float*)d_in[idx++];
    const float* dW1   = (const float*)d_in[idx++];
    const float* dB1   = (const float*)d_in[idx++];
    const float* dW2   = (const float*)d_in[idx++];
    const float* dB2   = (const float*)d_in[idx++];
    const float* dLn1g = (const float*)d_in[idx++];
    const float* dLn1b = (const float*)d_in[idx++];
    const float* dLn2g = (const float*)d_in[idx++];
    const float* dLn2b = (const float*)d_in[idx++];
    const float* dLn3g = (const float*)d_in[idx++];
    const float* dLn3b = (const float*)d_in[idx++];

    float* ws = (float*)d_ws;
    u16* OV    = (u16*)ws;
    u16* QKVb  = OV;
    u16* H1b   = OV;
    u16* CKVb  = OV;
    u16* AFb    = (u16*)(ws + 8388608);
    float* Dpart = ws + 8388608;
    float* X1   = ws + 10485760;
    float* XOUT = ws + 14680064;
    float* SuffV = ws + 18874368;
    float* Opart = ws + 18874368;
    float* DA    = ws + 20103168;
    float* Y1   = ws + 20512768;
    float* Y2   = ws + 20922368;
    float* YOUT = ws + 21331968;
    u16* ub  = (u16*)(ws + 21741568);
    u16* XBc = ub;
    u16* YB  = ub + 4194304;
    u16* Y1b = ub + 4603904;
    u16* Y2b = ub + 5013504;
    u16* DQb = ub + 5423104;
    u16* DAb = ub + 5832704;
    u16* DHb = ub + 6242304;
    u16* DQKVb = DHb;
    u16* WB  = ub + 7880704;

    const unsigned eQKVT = 0, eW1T = 1572864, eW2T = 3670016,
                   dQKV1T = 5767168, dWq2T = 7340032, dKV2T = 7864320,
                   dW1T = 8912896, dW2T = 11010048;

    auto gemm = [&](const u16* A, const u16* Bt, const float* bias, float* Cf, u16* Cb,
                    int M, int K, int N, int relu) {
        dim3 grid(N / 128, (M + 127) / 128);
        hipLaunchKernelGGL(gemm_mfma_kernel, grid, dim3(256), 0, stream,
                           A, Bt, bias, Cf, Cb, M, K, N, relu);
    };
    auto gemm64 = [&](const u16* A, const u16* Bt, const float* bias, float* Cf, u16* Cb,
                      int M, int K, int N, int relu) {
        dim3 grid(N / 64, (M + 63) / 64);
        hipLaunchKernelGGL(gemm64_kernel, grid, dim3(256), 0, stream,
                           A, Bt, bias, Cf, Cb, M, K, N, relu);
    };
    auto ln = [&](const float* Xf, const u16* Xb, const float* R, const float* g,
                  const float* bta, float* O, u16* Ob, int rows) {
        hipLaunchKernelGGL(ln_kernel, dim3((rows + 3) / 4), dim3(256), 0, stream,
                           Xf, Xb, R, g, bta, O, Ob, rows);
    };

    // ---- batched weight transposes + input converts ----
    {
        WT9 w9;
        const float* s9[9] = {eWq, eWk, eWv, dWq1, dWk1, dWv1, dWq2, dWk2, dWv2};
        const unsigned d9[9] = {eQKVT, eQKVT + 262144, eQKVT + 524288,
                                dQKV1T, dQKV1T + 262144, dQKV1T + 524288,
                                dWq2T, dKV2T, dKV2T + 262144};
        const unsigned o9[9] = {786432, 786432, 786432, 786432, 786432, 786432,
                                262144, 524288, 524288};
        for (int i = 0; i < 9; ++i) { w9.src[i] = s9[i]; w9.dst[i] = d9[i]; w9.os[i] = o9[i]; }
        hipLaunchKernelGGL(wtrans9_kernel, dim3(16, 16, 18), dim3(256), 0, stream, w9, WB);

        WT4 w4;
        const float* s4[4] = {eW1, eW2, dW1, dW2};
        const unsigned d4[4] = {eW1T, eW2T, dW1T, dW2T};
        const int K4[4] = {512, 2048, 512, 2048};
        const int N4[4] = {2048, 512, 2048, 512};
        for (int i = 0; i < 4; ++i) { w4.src[i] = s4[i]; w4.dst[i] = d4[i]; w4.K[i] = K4[i]; w4.N[i] = N4[i]; }
        hipLaunchKernelGGL(wtrans4_kernel, dim3(64, 64, 8), dim3(256), 0, stream, w4, WB);

        const int n0 = ME * DM, n1 = MD * DM;
        hipLaunchKernelGGL(conv2_kernel, dim3((n0 + n1) / 8 / 256), dim3(256), 0, stream,
                           x0, XBc, n0, y0, YB, n1);
    }

    const int BS = DM;
    const int B1S = DFF;

    // ---------------- encoder ----------------
    const float* xin = x0;
    for (int i = 0; i < L; ++i) {
        gemm(XBc, WB + eQKVT + (size_t)i * 786432, nullptr, nullptr, QKVb, ME, DM, 1536, 0);
        {
            dim3 grid(T_ENC / 128, 8, B);
            hipLaunchKernelGGL(attn_mfma_kernel, grid, dim3(256), 0, stream,
                               QKVb, QKVb + 512, QKVb + 1024, AFb,
                               T_ENC, T_ENC, 1536, 1536, 512);
        }
        ln(nullptr, AFb, xin, eLn1g + i * BS, eLn1b + i * BS, X1, XBc, ME);
        gemm(XBc, WB + eW1T + (size_t)i * 1048576, eB1 + i * B1S, nullptr, H1b, ME, DM, DFF, 1);
        gemm(H1b, WB + eW2T + (size_t)i * 1048576, eB2 + i * BS, nullptr, AFb, ME, DFF, DM, 0);
        ln(nullptr, AFb, X1, eLn2g + i * BS, eLn2b + i * BS, XOUT, XBc, ME);
        xin = XOUT;
    }

    // ---- cross K/V for BOTH decoder layers in one GEMM ----
    gemm(XBc, WB + dKV2T, nullptr, nullptr, CKVb, ME, DM, 2048, 0);

    // ---------------- decoder ----------------
    const float* yin = y0;
    for (int i = 0; i < L; ++i) {
        gemm64(YB, WB + dQKV1T + (size_t)i * 786432, nullptr, nullptr, DQKVb, MD, DM, 1536, 0);
        hipLaunchKernelGGL(suffv_kernel, dim3(B, 8), dim3(64), 0, stream,
                           DQKVb + 1024, SuffV, T_DEC, 1536);
        {
            dim3 grid((T_DEC + 127) / 128, 8, B);
            hipLaunchKernelGGL(attn_causal_kernel, grid, dim3(256), 0, stream,
                               DQKVb, DQKVb + 512, DQKVb + 1024, SuffV, DAb,
                               T_DEC, T_DEC, 1536, 1536, 512);
        }
        ln(nullptr, DAb, yin, dLn1g + i * BS, dLn1b + i * BS, Y1, Y1b, MD);
        gemm64(Y1b, WB + dWq2T + (size_t)i * 262144, nullptr, nullptr, DQb, MD, DM, DM, 0);
        {
            dim3 grid((T_DEC + 63) / 64, 8, B * NSPLIT);
            hipLaunchKernelGGL(attn_split_kernel, grid, dim3(256), 0, stream,
                               DQb, CKVb + (size_t)i * 1024, CKVb + (size_t)i * 1024 + 512,
                               Opart, Dpart, T_DEC, T_ENC, 512, 2048, NSPLIT);
            hipLaunchKernelGGL(combine_ln_kernel, dim3((MD + 3) / 4), dim3(256), 0, stream,
                               Opart, Dpart, NSPLIT, MD,
                               Y1, dLn2g + i * BS, dLn2b + i * BS, Y2, Y2b);
        }
        gemm64(Y2b, WB + dW1T + (size_t)i * 1048576, dB1 + i * B1S, nullptr, DHb, MD, DM, DFF, 1);
        gemm64(DHb, WB + dW2T + (size_t)i * 1048576, dB2 + i * BS, DA, nullptr, MD, DFF, DM, 0);
        float* yout = (i == L - 1) ? (float*)d_out : YOUT;
        ln(DA, nullptr, Y2, dLn3g + i * BS, dLn3b + i * BS, yout,
           (i == L - 1) ? nullptr : YB, MD);
        yin = yout;
    }
}